// Round 5
// baseline (1166.114 us; speedup 1.0000x reference)
//
#include <hip/hip_runtime.h>
#include <math.h>

// Problem constants (match reference setup_inputs)
constexpr int Bc = 64, Nc = 2048, Dc = 512, Hc = 512;
constexpr long long Mc = (long long)Bc * Nc;   // 131072 rows
constexpr int BM = 128, BN = 128, BK = 32;
constexpr int LDA_ = 132;                       // padded LDS leading dim for As (floats)

// async global->LDS, 16B per lane, dest = wave-uniform base + lane*16
__device__ __forceinline__ void gload16(const float* g, void* lds) {
    __builtin_amdgcn_global_load_lds(
        (const __attribute__((address_space(1))) void*)g,
        (__attribute__((address_space(3))) void*)lds, 16, 0, 0);
}

// ---------------------------------------------------------------------------
// GEMM: Hout[M][H] = X[M][D] @ W[D][H] + bias, fused per-block column
// sum/sumsq partials -> fp64 atomics. 256 threads, 8x8 micro-tile/thread.
// B staged via global_load_lds into double-buffered Bs (issue-early so the
// vmcnt(0) drain at the barrier finds loads already landed). A staged via
// register prefetch + LDS transpose (padded, 2-way read aliasing = free).
// ---------------------------------------------------------------------------
__global__ __launch_bounds__(256) void gemm_fused(const float* __restrict__ X,
                                                  const float* __restrict__ W,
                                                  const float* __restrict__ bias,
                                                  float* __restrict__ Hout,
                                                  double* __restrict__ stats /*[2][512]*/)
{
    __shared__ float As[BK][LDA_];          // [k][m] transposed A tile, 16.5 KB
    __shared__ float Bs[2][BK][BN];         // double-buffered B tile, 32 KB
    __shared__ float sred[4][128];          // stats cross-wave reduce, 2 KB

    // XCD-chunked swizzle: wg i -> XCD i&7 (round-robin heuristic). Give each
    // XCD 128 consecutive bm panels, bn fastest -> A panel L2-resident.
    const int wgid = blockIdx.x;            // 0..4095
    const int xcd  = wgid & 7;
    const int slot = wgid >> 3;             // 0..511
    const int bm   = xcd * 128 + (slot >> 2);
    const int bn   = slot & 3;
    const int m0 = bm * BM, n0 = bn * BN;

    const int tid = threadIdx.x;
    const int wave = tid >> 6, lane = tid & 63;
    const int wm = wave >> 1, wn = wave & 1;
    const int lm = lane >> 3, ln = lane & 7;
    const int am = wm * 64 + lm * 8;        // row offset within tile
    const int an = wn * 64 + ln * 8;        // col offset within tile

    // A staging map: thread -> (row ar, k-quad ak), 4 row-passes of 32
    const int ar = tid >> 3;                // 0..31
    const int ak = (tid & 7) << 2;          // 0..28
    const float* aPtr = X + (size_t)(m0 + ar) * Dc + ak;

    // B global_load_lds map: instr t covers k rows wave*8+2t+(lane>>5)
    const int bkw = wave * 8 + (lane >> 5);
    const int bc  = (lane & 31) << 2;
    const float* wPtr = W + (size_t)bkw * Hc + n0 + bc;
    char* bsBase = (char*)&Bs[0][0][0];

    // prologue: issue B(0) -> Bs[0]; load A(0) -> regs
#pragma unroll
    for (int t = 0; t < 4; ++t) {
        int off = __builtin_amdgcn_readfirstlane(wave * 4096 + t * 1024);
        gload16(wPtr + (size_t)(2 * t) * Hc, bsBase + off);
    }
    float4 areg[4];
#pragma unroll
    for (int p = 0; p < 4; ++p) areg[p] = *(const float4*)(aPtr + (size_t)p * 32 * Dc);

    float acc[8][8];
#pragma unroll
    for (int i = 0; i < 8; ++i)
#pragma unroll
        for (int j = 0; j < 8; ++j) acc[i][j] = 0.0f;

    for (int it = 0; it < 16; ++it) {
        const int cur = it & 1;
        __syncthreads();                    // waves done reading As/Bs[cur^1]; drains landed loads
        // A transpose-write (LDT=132 -> 4-way on writes, 16 writes/tile: negligible)
#pragma unroll
        for (int p = 0; p < 4; ++p) {
            const int r = ar + 32 * p;
            As[ak + 0][r] = areg[p].x;  As[ak + 1][r] = areg[p].y;
            As[ak + 2][r] = areg[p].z;  As[ak + 3][r] = areg[p].w;
        }
        __syncthreads();                    // As(t) + Bs[cur] ready
        if (it < 15) {
            const int ktn = (it + 1) * BK;
            // issue B(t+1) now: lands during the 4096-cycle FMA block below
#pragma unroll
            for (int t = 0; t < 4; ++t) {
                int off = __builtin_amdgcn_readfirstlane((cur ^ 1) * 16384 + wave * 4096 + t * 1024);
                gload16(wPtr + (size_t)(ktn + 2 * t) * Hc, bsBase + off);
            }
#pragma unroll
            for (int p = 0; p < 4; ++p)
                areg[p] = *(const float4*)(aPtr + (size_t)p * 32 * Dc + ktn);
        }
        const float (*Bcur)[BN] = Bs[cur];
#pragma unroll 8
        for (int k = 0; k < BK; ++k) {
            const float* ap = &As[k][am];
            const float* bp = &Bcur[k][an];
            float a_[8], b_[8];
#pragma unroll
            for (int u = 0; u < 8; ++u) { a_[u] = ap[u]; b_[u] = bp[u]; }
#pragma unroll
            for (int i = 0; i < 8; ++i)
#pragma unroll
                for (int j = 0; j < 8; ++j)
                    acc[i][j] = fmaf(a_[i], b_[j], acc[i][j]);
        }
    }

    // epilogue: bias add, store, per-block column sum/sumsq
    float4 c0 = *(const float4*)&bias[n0 + an];
    float4 c1 = *(const float4*)&bias[n0 + an + 4];
    float bz[8] = {c0.x, c0.y, c0.z, c0.w, c1.x, c1.y, c1.z, c1.w};
    float s_[8], q_[8];
#pragma unroll
    for (int u = 0; u < 8; ++u) { s_[u] = 0.f; q_[u] = 0.f; }
#pragma unroll
    for (int i = 0; i < 8; ++i) {
        float v[8];
#pragma unroll
        for (int j = 0; j < 8; ++j) {
            v[j] = acc[i][j] + bz[j];
            s_[j] += v[j];
            q_[j] = fmaf(v[j], v[j], q_[j]);
        }
        const size_t row = (size_t)(m0 + am + i);
        float4 o0 = {v[0], v[1], v[2], v[3]};
        float4 o1 = {v[4], v[5], v[6], v[7]};
        *(float4*)&Hout[row * Hc + n0 + an]     = o0;
        *(float4*)&Hout[row * Hc + n0 + an + 4] = o1;
    }
    // reduce over lm (lane bits 3..5): every lane ends with its octet's sums
#pragma unroll
    for (int off = 8; off < 64; off <<= 1) {
#pragma unroll
        for (int u = 0; u < 8; ++u) {
            s_[u] += __shfl_xor(s_[u], off);
            q_[u] += __shfl_xor(q_[u], off);
        }
    }
    if (lm == 0) {
#pragma unroll
        for (int u = 0; u < 8; ++u) {
            sred[wave][ln * 16 + u]     = s_[u];
            sred[wave][ln * 16 + 8 + u] = q_[u];
        }
    }
    __syncthreads();
    {
        const int wn2 = tid >> 7, ln2 = (tid >> 4) & 7, u = tid & 15;
        // waves with this wn: wave=wn2 (wm=0) and wave=wn2+2 (wm=1)
        float v = sred[wn2][ln2 * 16 + u] + sred[wn2 + 2][ln2 * 16 + u];
        const int col = n0 + wn2 * 64 + ln2 * 8 + (u & 7);
        atomicAdd(&stats[(u >> 3) * Hc + col], (double)v);
    }
}

// ---------------------------------------------------------------------------
__global__ __launch_bounds__(256) void zero_stats(double* __restrict__ s)
{
    int i = blockIdx.x * 256 + threadIdx.x;
    if (i < 1024) s[i] = 0.0;
}

__global__ __launch_bounds__(256) void finalize_stats(const double* __restrict__ sum,
                                                      const double* __restrict__ sumsq,
                                                      const float* __restrict__ gamma,
                                                      const float* __restrict__ beta,
                                                      float* __restrict__ scale,
                                                      float* __restrict__ shift)
{
    int c = blockIdx.x * 256 + threadIdx.x;
    if (c < Hc) {
        double mu  = sum[c] / (double)Mc;
        double var = sumsq[c] / (double)Mc - mu * mu;
        double rstd = 1.0 / sqrt(var + 1e-5);
        float a = (float)rstd * gamma[c];
        scale[c] = a;
        shift[c] = beta[c] - (float)mu * a;
    }
}

// ---------------------------------------------------------------------------
// Heads: one wave per (b, pos); BN+ReLU the row, dot with W[C], argmax.
// Both heads in one launch (wave-uniform branch). C templated so p[] stays
// in registers (runtime-indexed arrays go to scratch).
// ---------------------------------------------------------------------------
template <int C>
__device__ __forceinline__ void head_body(int hw, const int* __restrict__ idx,
                                          const float* __restrict__ Wc,
                                          const float* __restrict__ bc,
                                          const float* __restrict__ Hbuf,
                                          const float* __restrict__ scale,
                                          const float* __restrict__ shift,
                                          float* __restrict__ out, int lane)
{
    const int b = hw >> 10, pos = hw & 1023;
    const int n = idx[pos];
    const size_t row = (size_t)b * Nc + n;

    const int i0 = lane * 8;
    float4 h0 = *(const float4*)&Hbuf[row * Hc + i0];
    float4 h1 = *(const float4*)&Hbuf[row * Hc + i0 + 4];
    float4 s0 = *(const float4*)&scale[i0];
    float4 s1 = *(const float4*)&scale[i0 + 4];
    float4 t0 = *(const float4*)&shift[i0];
    float4 t1 = *(const float4*)&shift[i0 + 4];

    float v[8];
    v[0] = fmaxf(fmaf(h0.x, s0.x, t0.x), 0.f);
    v[1] = fmaxf(fmaf(h0.y, s0.y, t0.y), 0.f);
    v[2] = fmaxf(fmaf(h0.z, s0.z, t0.z), 0.f);
    v[3] = fmaxf(fmaf(h0.w, s0.w, t0.w), 0.f);
    v[4] = fmaxf(fmaf(h1.x, s1.x, t1.x), 0.f);
    v[5] = fmaxf(fmaf(h1.y, s1.y, t1.y), 0.f);
    v[6] = fmaxf(fmaf(h1.z, s1.z, t1.z), 0.f);
    v[7] = fmaxf(fmaf(h1.w, s1.w, t1.w), 0.f);

    float p[C];
#pragma unroll
    for (int c = 0; c < C; ++c) p[c] = 0.f;
#pragma unroll
    for (int u = 0; u < 8; ++u) {
        const float* wrow = Wc + (size_t)(i0 + u) * C;
#pragma unroll
        for (int c = 0; c < C; ++c) p[c] = fmaf(v[u], wrow[c], p[c]);
    }
#pragma unroll
    for (int off = 32; off; off >>= 1)
#pragma unroll
        for (int c = 0; c < C; ++c) p[c] += __shfl_xor(p[c], off);

    if (lane == 0) {
        float best = p[0] + bc[0];
        int bi = 0;
#pragma unroll
        for (int c = 1; c < C; ++c) {
            float l = p[c] + bc[c];
            if (l > best) { best = l; bi = c; }   // strict >: first-index tie-break = jnp.argmax
        }
        out[row] = (float)bi;
    }
}

__global__ __launch_bounds__(256) void heads_kernel(const float* __restrict__ Hbuf,
                                                    const float* __restrict__ scale,
                                                    const float* __restrict__ shift,
                                                    const float* __restrict__ Wa,
                                                    const float* __restrict__ ba,
                                                    const int* __restrict__ idx_a,
                                                    const float* __restrict__ Wb,
                                                    const float* __restrict__ bb,
                                                    const int* __restrict__ idx_b,
                                                    float* __restrict__ out)
{
    const int wid = blockIdx.x * 4 + (threadIdx.x >> 6);
    const int lane = threadIdx.x & 63;
    if (wid < 65536)
        head_body<3>(wid, idx_a, Wa, ba, Hbuf, scale, shift, out, lane);
    else
        head_body<5>(wid - 65536, idx_b, Wb, bb, Hbuf, scale, shift, out, lane);
}

// ---------------------------------------------------------------------------
extern "C" void kernel_launch(void* const* d_in, const int* in_sizes, int n_in,
                              void* d_out, int out_size, void* d_ws, size_t ws_size,
                              hipStream_t stream)
{
    (void)in_sizes; (void)n_in; (void)out_size; (void)ws_size;
    const float* x     = (const float*)d_in[0];
    const float* W1    = (const float*)d_in[1];
    const float* b1    = (const float*)d_in[2];
    const float* gamma = (const float*)d_in[3];
    const float* beta  = (const float*)d_in[4];
    const float* Wa    = (const float*)d_in[5];
    const float* ba    = (const float*)d_in[6];
    const float* Wb    = (const float*)d_in[7];
    const float* bb    = (const float*)d_in[8];
    const int*   idx_a = (const int*)d_in[9];
    const int*   idx_b = (const int*)d_in[10];
    float* out = (float*)d_out;

    char* ws = (char*)d_ws;
    float*  Hbuf  = (float*)ws;                                  // 131072*512*4 = 256 MiB
    double* stats = (double*)(ws + (size_t)Mc * Hc * 4);         // 1024 doubles (sum | sumsq)
    float*  scale = (float*)((char*)stats + 1024 * sizeof(double));
    float*  shift = scale + Hc;

    zero_stats<<<4, 256, 0, stream>>>(stats);
    gemm_fused<<<4096, 256, 0, stream>>>(x, W1, b1, Hbuf, stats);
    finalize_stats<<<2, 256, 0, stream>>>(stats, stats + 512, gamma, beta, scale, shift);
    heads_kernel<<<32768, 256, 0, stream>>>(Hbuf, scale, shift, Wa, ba, idx_a, Wb, bb, idx_b, out);
}